// Round 13
// baseline (174.726 us; speedup 1.0000x reference)
//
#include <hip/hip_runtime.h>
#include <hip/hip_bf16.h>

// ---------------------------------------------------------------------------
// IrrepsLinear via bf16 hi/lo-split MFMA (gfx950), round 13.
//   out0 = (x0 @ W0 + modal @ W0m) / sqrt(130)      x0: [N,128], W0: 128x128
//   out1 = einsum('nim,io', x1, W1) / 8             x1: [N,64,3], W1: 64x64
//   out2 = einsum('nim,io', x2, W2) / sqrt(32)      x2: [N,32,5], W2: 32x32
// v = hi + lo (bf16 RNE); v*w ~ vh*wh + vl*wh + vh*wl (3 MFMAs).
// Round-13 vs r8 (159.5us best):
//   - x staged via __builtin_amdgcn_global_load_lds (width=16) into a RAW
//     fp32 LDS region: DMA(P+1) issued during compute(P), ZERO prefetch
//     VGPRs, drained by the vmcnt(0) __syncthreads already emits.
//   - bf16 split moved to frag-read (in-register, 2x dup across col-halves).
//   - Raw rows 512/768/640 B are 32-way bank hazards -> XOR swizzle
//     (row&7)<<4 applied via pre-swizzled DMA SOURCE (linear dest) and
//     swizzled ds_read (rule #21); XOR is row-preserving for all 3 strides.
//   - Same OUT fp32 epilogue + wave-contiguous streams as r8. LDS 49664.
// ---------------------------------------------------------------------------

typedef __attribute__((ext_vector_type(8))) short  short8;   // bf16x8 frag
typedef __attribute__((ext_vector_type(4))) float  f32x4;    // acc frag

#define NTH 256
#define BR  32

// ws layout in ushort units
#define W0H 0
#define W0L 16384
#define W1H 32768
#define W1L 36864
#define W2H 40960
#define W2L 41984
// total 43008 ushorts = 86016 bytes of d_ws

// --------------------------- split helpers ---------------------------------
__device__ __forceinline__ unsigned bc2(__hip_bfloat162 h) {
    unsigned u; __builtin_memcpy(&u, &h, 4); return u;
}

struct HL4 { uint2 h, l; };

__device__ __forceinline__ HL4 split4(float a, float b, float c, float d) {
    __hip_bfloat162 h01 = __float22bfloat162_rn({a, b});
    __hip_bfloat162 h23 = __float22bfloat162_rn({c, d});
    float ra = a - __low2float(h01),  rb = b - __high2float(h01);
    float rc = c - __low2float(h23),  rd = d - __high2float(h23);
    __hip_bfloat162 l01 = __float22bfloat162_rn({ra, rb});
    __hip_bfloat162 l23 = __float22bfloat162_rn({rc, rd});
    HL4 r;
    r.h = make_uint2(bc2(h01), bc2(h23));
    r.l = make_uint2(bc2(l01), bc2(l23));
    return r;
}

__device__ __forceinline__ void packhl(const HL4& p, const HL4& q,
                                       short8& hi, short8& lo) {
    uint4 h4 = make_uint4(p.h.x, p.h.y, q.h.x, q.h.y);
    uint4 l4 = make_uint4(p.l.x, p.l.y, q.l.x, q.l.y);
    __builtin_memcpy(&hi, &h4, 16);
    __builtin_memcpy(&lo, &l4, 16);
}

__device__ __forceinline__ void split_w(float v, unsigned short& h, unsigned short& l) {
    __hip_bfloat16 hb = __float2bfloat16(v);
    float r = v - __bfloat162float(hb);
    __hip_bfloat16 lb = __float2bfloat16(r);
    __builtin_memcpy(&h, &hb, 2);
    __builtin_memcpy(&l, &lb, 2);
}

// async global -> LDS, 16 bytes per lane; lds_base must be wave-uniform.
__device__ __forceinline__ void dma16(const float* g, char* lds_base) {
    __builtin_amdgcn_global_load_lds(
        (const __attribute__((address_space(1))) unsigned int*)g,
        (__attribute__((address_space(3))) unsigned int*)lds_base,
        16, 0, 0);
}

// --------------------------- weight prep kernel ----------------------------
// B-frag order: slot s = ((ct*NKT + kt)*64 + lane)*8 + j holds W[k][col],
//   col = ct*16 + (lane&15), k = kt*32 + (lane>>4)*8 + j.
__global__ void prep_weights(const float* __restrict__ W0,
                             const float* __restrict__ W1,
                             const float* __restrict__ W2,
                             unsigned short* __restrict__ ws) {
    const int s0     = blockIdx.x * blockDim.x + threadIdx.x;
    const int STRIDE = gridDim.x * blockDim.x;
    for (int s = s0; s < 16384; s += STRIDE) {     // W0: ct 0..7, kt 0..3
        int j = s & 7, l = (s >> 3) & 63, kt = (s >> 9) & 3, ct = s >> 11;
        int col = ct * 16 + (l & 15);
        int k   = kt * 32 + (l >> 4) * 8 + j;
        unsigned short h, lo;
        split_w(W0[k * 128 + col], h, lo);
        ws[W0H + s] = h; ws[W0L + s] = lo;
    }
    for (int s = s0; s < 4096; s += STRIDE) {      // W1: ct 0..3, kt 0..1
        int j = s & 7, l = (s >> 3) & 63, kt = (s >> 9) & 1, ct = s >> 10;
        int col = ct * 16 + (l & 15);
        int k   = kt * 32 + (l >> 4) * 8 + j;
        unsigned short h, lo;
        split_w(W1[k * 64 + col], h, lo);
        ws[W1H + s] = h; ws[W1L + s] = lo;
    }
    for (int s = s0; s < 1024; s += STRIDE) {      // W2: ct 0..1, kt = 0
        int j = s & 7, l = (s >> 3) & 63, ct = s >> 9;
        int col = ct * 16 + (l & 15);
        int k   = (l >> 4) * 8 + j;
        unsigned short h, lo;
        split_w(W2[k * 32 + col], h, lo);
        ws[W2H + s] = h; ws[W2L + s] = lo;
    }
}

#define MFMA(a, b, c) __builtin_amdgcn_mfma_f32_16x16x32_bf16((a), (b), (c), 0, 0, 0)

// ------------------------------ main kernel --------------------------------
// 4 waves/block; wave w: rows rb0=(w>>1)*16, col-half ch=w&1.
// RAW region [0,24576): fp32 x tile of current phase, source-swizzled so
//   LDS[q] = data[q ^ ((row(q)&7)<<4)]; rows: A 512B, B 768B, C 640B.
// OUT region [24576,49664): A f32 [32][132]; B f32 [32][196]; C f32 [32][164]
__global__ __launch_bounds__(NTH, 3) void irreps_mfma_kernel(
    const float* __restrict__ x,
    const float* __restrict__ modal_attr,
    const float* __restrict__ W0m,
    const unsigned short* __restrict__ wsf,
    const int*   __restrict__ batch,
    float*       __restrict__ out,
    int N)
{
    __shared__ __align__(16) char ldsb[49664];
    char*  raw  = ldsb;
    float* ldsf = reinterpret_cast<float*>(ldsb + 24576);

    const int tid  = threadIdx.x;
    const int w    = tid >> 6;
    const int l    = tid & 63;
    const int r    = l & 15;
    const int kg   = l >> 4;
    const int rb0  = (w >> 1) * 16;
    const int ch   = w & 1;
    const int row0 = blockIdx.x * BR;
    const int arow = rb0 + r;
    const int sw   = (arow & 7) << 4;

    // ---- issue DMA A: 16 KB raw fp32, 16 chunks of 1 KB, 4 per wave ----
    #pragma unroll
    for (int i = 0; i < 4; ++i) {
        int c   = w * 4 + i;
        int o   = c * 1024 + l * 16;
        int row = o >> 9;                       // /512
        int so  = o ^ ((row & 7) << 4);
        int col = so & 511;
        int n   = row0 + row; n = n < N ? n : N - 1;
        dma16(x + (size_t)n * 480 + (col >> 2), raw + c * 1024);
    }

    // modal lookups overlap the DMA
    float am0[4], am1[4];
    #pragma unroll
    for (int reg = 0; reg < 4; ++reg) {
        int n  = row0 + rb0 + kg * 4 + reg;
        int nc = n < N ? n : N - 1;
        int g  = batch[nc];
        am0[reg] = modal_attr[2 * g];
        am1[reg] = modal_attr[2 * g + 1];
    }
    __syncthreads();                                            // bar 1 (A in LDS)

    // ---- frags A: raw -> split -> regs ----
    short8 xah[4], xal[4];
    #pragma unroll
    for (int kt = 0; kt < 4; ++kt) {
        int b0 = arow * 512 + kt * 128 + kg * 32;
        f32x4 a = *reinterpret_cast<const f32x4*>(raw + (b0 ^ sw));
        f32x4 b = *reinterpret_cast<const f32x4*>(raw + ((b0 + 16) ^ sw));
        HL4 p = split4(a[0], a[1], a[2], a[3]);
        HL4 q = split4(b[0], b[1], b[2], b[3]);
        packhl(p, q, xah[kt], xal[kt]);
    }
    __syncthreads();                                            // bar 2 (raw free)

    // ---- slot: issue DMA B + compute A -> OUT ----
    #pragma unroll
    for (int i = 0; i < 6; ++i) {                // 24 KB, 24 chunks, 6/wave
        int c   = w * 6 + i;
        int o   = c * 1024 + l * 16;
        int row = o / 768;
        int so  = o ^ ((row & 7) << 4);
        int col = so - row * 768;
        int n   = row0 + row; n = n < N ? n : N - 1;
        dma16(x + (size_t)n * 480 + 128 + (col >> 2), raw + c * 1024);
    }
    {
        #pragma unroll
        for (int ci = 0; ci < 4; ++ci) {
            int ct = ch * 4 + ci;
            f32x4 acc = {0.f, 0.f, 0.f, 0.f};
            #pragma unroll
            for (int kt = 0; kt < 4; ++kt) {
                int b = ct * 4 + kt;
                short8 bh = *reinterpret_cast<const short8*>(wsf + W0H + (size_t)(b * 64 + l) * 8);
                short8 bl = *reinterpret_cast<const short8*>(wsf + W0L + (size_t)(b * 64 + l) * 8);
                acc = MFMA(xah[kt], bh, acc);
                acc = MFMA(xal[kt], bh, acc);
                acc = MFMA(xah[kt], bl, acc);
            }
            int col = ct * 16 + r;
            float wm0 = W0m[col], wm1 = W0m[128 + col];
            #pragma unroll
            for (int reg = 0; reg < 4; ++reg)
                ldsf[(rb0 + kg * 4 + reg) * 132 + col] =
                    (acc[reg] + am0[reg] * wm0 + am1[reg] * wm1) * 0.08770580193070293f;
        }
    }
    __syncthreads();                                            // bar 3 (B in LDS, OUT-A ready)

    // ---- slot: frags B (raw) + stream A (OUT) ----
    short8 xbh[3][2], xbl[3][2];
    #pragma unroll
    for (int kt = 0; kt < 2; ++kt) {
        int b0 = arow * 768 + kt * 384 + kg * 96;
        float f[24];
        #pragma unroll
        for (int q = 0; q < 6; ++q) {
            f32x4 v = *reinterpret_cast<const f32x4*>(raw + ((b0 + q * 16) ^ sw));
            f[q * 4 + 0] = v[0]; f[q * 4 + 1] = v[1];
            f[q * 4 + 2] = v[2]; f[q * 4 + 3] = v[3];
        }
        #pragma unroll
        for (int m = 0; m < 3; ++m) {
            HL4 p = split4(f[0 + m], f[3 + m], f[6 + m],  f[9 + m]);
            HL4 q = split4(f[12 + m], f[15 + m], f[18 + m], f[21 + m]);
            packhl(p, q, xbh[m][kt], xbl[m][kt]);
        }
    }
    {   // stream out0: 32 rows x 128 f32
        #pragma unroll
        for (int j = 0; j < 4; ++j) {
            int idx = tid + j * NTH;
            int row = idx >> 5, c4 = idx & 31;
            int n   = row0 + row;
            if (n < N)
                *reinterpret_cast<float4*>(out + (size_t)n * 480 + c4 * 4) =
                    *reinterpret_cast<const float4*>(ldsf + row * 132 + c4 * 4);
        }
    }
    __syncthreads();                                            // bar 4 (raw/OUT free)

    // ---- slot: issue DMA C + compute B -> OUT ----
    #pragma unroll
    for (int i = 0; i < 5; ++i) {                // 20 KB, 20 chunks, 5/wave
        int c   = w * 5 + i;
        int o   = c * 1024 + l * 16;
        int row = o / 640;
        int so  = o ^ ((row & 7) << 4);
        int col = so - row * 640;
        int n   = row0 + row; n = n < N ? n : N - 1;
        dma16(x + (size_t)n * 480 + 320 + (col >> 2), raw + c * 1024);
    }
    {
        #pragma unroll
        for (int ci = 0; ci < 2; ++ci) {
            int ct = ch * 2 + ci;
            short8 bh[2], bl[2];
            #pragma unroll
            for (int kt = 0; kt < 2; ++kt) {
                int b = ct * 2 + kt;
                bh[kt] = *reinterpret_cast<const short8*>(wsf + W1H + (size_t)(b * 64 + l) * 8);
                bl[kt] = *reinterpret_cast<const short8*>(wsf + W1L + (size_t)(b * 64 + l) * 8);
            }
            #pragma unroll
            for (int m = 0; m < 3; ++m) {
                f32x4 acc = {0.f, 0.f, 0.f, 0.f};
                #pragma unroll
                for (int kt = 0; kt < 2; ++kt) {
                    acc = MFMA(xbh[m][kt], bh[kt], acc);
                    acc = MFMA(xbl[m][kt], bh[kt], acc);
                    acc = MFMA(xbh[m][kt], bl[kt], acc);
                }
                int col = 3 * (ct * 16 + r) + m;
                #pragma unroll
                for (int reg = 0; reg < 4; ++reg)
                    ldsf[(rb0 + kg * 4 + reg) * 196 + col] = acc[reg] * 0.125f;
            }
        }
    }
    __syncthreads();                                            // bar 5 (C in LDS, OUT-B ready)

    // ---- slot: frags C (raw) + stream B (OUT) ----
    short8 xch[5], xcl[5];
    {
        int b0 = arow * 640 + kg * 160;
        float f[40];
        #pragma unroll
        for (int q = 0; q < 10; ++q) {
            f32x4 v = *reinterpret_cast<const f32x4*>(raw + ((b0 + q * 16) ^ sw));
            f[q * 4 + 0] = v[0]; f[q * 4 + 1] = v[1];
            f[q * 4 + 2] = v[2]; f[q * 4 + 3] = v[3];
        }
        #pragma unroll
        for (int m = 0; m < 5; ++m) {
            HL4 p = split4(f[0 + m],  f[5 + m],  f[10 + m], f[15 + m]);
            HL4 q = split4(f[20 + m], f[25 + m], f[30 + m], f[35 + m]);
            packhl(p, q, xch[m], xcl[m]);
        }
    }
    {   // stream out1: 32 rows x 192 f32
        #pragma unroll
        for (int j = 0; j < 6; ++j) {
            int idx = tid + j * NTH;
            int row = idx / 48, c4 = idx - row * 48;
            int n   = row0 + row;
            if (n < N)
                *reinterpret_cast<float4*>(out + (size_t)n * 480 + 128 + c4 * 4) =
                    *reinterpret_cast<const float4*>(ldsf + row * 196 + c4 * 4);
        }
    }
    __syncthreads();                                            // bar 6 (OUT free)

    // ---- compute C -> OUT ----
    {
        int ct = ch;
        short8 bh = *reinterpret_cast<const short8*>(wsf + W2H + (size_t)(ct * 64 + l) * 8);
        short8 bl = *reinterpret_cast<const short8*>(wsf + W2L + (size_t)(ct * 64 + l) * 8);
        #pragma unroll
        for (int m = 0; m < 5; ++m) {
            f32x4 acc = {0.f, 0.f, 0.f, 0.f};
            acc = MFMA(xch[m], bh, acc);
            acc = MFMA(xcl[m], bh, acc);
            acc = MFMA(xch[m], bl, acc);
            int col = 5 * (ct * 16 + r) + m;
            #pragma unroll
            for (int reg = 0; reg < 4; ++reg)
                ldsf[(rb0 + kg * 4 + reg) * 164 + col] = acc[reg] * 0.17677669529663687f;
        }
    }
    __syncthreads();                                            // bar 7

    {   // stream out2: 32 rows x 160 f32
        #pragma unroll
        for (int j = 0; j < 5; ++j) {
            int idx = tid + j * NTH;
            int row = idx / 40, c4 = idx - row * 40;
            int n   = row0 + row;
            if (n < N)
                *reinterpret_cast<float4*>(out + (size_t)n * 480 + 320 + c4 * 4) =
                    *reinterpret_cast<const float4*>(ldsf + row * 164 + c4 * 4);
        }
    }
}

extern "C" void kernel_launch(void* const* d_in, const int* in_sizes, int n_in,
                              void* d_out, int out_size, void* d_ws, size_t ws_size,
                              hipStream_t stream) {
    const float* x     = (const float*)d_in[0];
    const float* modal = (const float*)d_in[1];
    const float* W0    = (const float*)d_in[2];
    const float* W0m   = (const float*)d_in[3];
    const float* W1    = (const float*)d_in[4];
    const float* W2    = (const float*)d_in[5];
    const int*   batch = (const int*)d_in[6];
    float* out = (float*)d_out;
    unsigned short* ws = (unsigned short*)d_ws;   // needs 86016 B

    const int N    = in_sizes[6];                 // 200000
    const int grid = (N + BR - 1) / BR;           // 6250 blocks

    prep_weights<<<84, NTH, 0, stream>>>(W0, W1, W2, ws);
    irreps_mfma_kernel<<<grid, NTH, 0, stream>>>(x, modal, W0m, ws, batch, out, N);
}